// Round 6
// baseline (78.742 us; speedup 1.0000x reference)
//
#include <hip/hip_runtime.h>
#include <hip/hip_bf16.h>

#define N_NODES 10000
#define N_EDGES 640000
#define D 128

#define NB 250                    // buckets, 40 dst-nodes each (250*40 = 10000)
#define BSTRIDE 256               // padded stride for bucket arrays
#define NCHUNK 256                // edge chunks
#define CHUNK (N_EDGES / NCHUNK)  // 2500
#define GEMM_BLOCKS 313           // ceil(10000/32)
#define CAP 4096                  // max edges/bucket (mean 2560, sigma~50 -> 30+ sigma headroom)

__device__ __forceinline__ unsigned short f2bf(float f) {
    unsigned int u = __float_as_uint(f);
    unsigned int r = (u + 0x7fffu + ((u >> 16) & 1u)) >> 16;  // RNE
    return (unsigned short)r;
}

// ---------------------------------------------------------------------------
// K1 (fused): blocks [0,NCHUNK) LDS-histogram dst-buckets (256 bins, 1KB);
// blocks [NCHUNK, +GEMM_BLOCKS) compute y = bf16(x @ W). Independent work.
// ---------------------------------------------------------------------------
__global__ __launch_bounds__(256) void hist_gemm(const float* __restrict__ x,
                                                 const float* __restrict__ W,
                                                 const int* __restrict__ dst,
                                                 unsigned short* __restrict__ y,
                                                 int* __restrict__ cnt_part) {
    __shared__ float sW[128 * 128];   // 64 KB (hist blocks reuse 1 KB of it)
    __shared__ float sx[32 * 128];    // 16 KB

    if (blockIdx.x < NCHUNK) {
        // ---- bucket histogram block ----
        int* h = (int*)sW;            // 256 ints
        h[threadIdx.x] = 0;
        __syncthreads();
        const int e0 = blockIdx.x * CHUNK;
        for (int i = threadIdx.x; i < CHUNK; i += 256)
            atomicAdd(&h[dst[e0 + i] / 40], 1);     // LDS atomic
        __syncthreads();
        cnt_part[blockIdx.x * BSTRIDE + threadIdx.x] = h[threadIdx.x];
        return;
    }

    // ---- GEMM block ----
    const int row0 = (blockIdx.x - NCHUNK) * 32;

    for (int i = threadIdx.x; i < 128 * 128 / 4; i += 256)
        ((float4*)sW)[i] = ((const float4*)W)[i];
    for (int i = threadIdx.x; i < 32 * 128 / 4; i += 256) {
        int r = row0 + (i >> 5);
        float4 v = make_float4(0.f, 0.f, 0.f, 0.f);
        if (r < N_NODES) v = ((const float4*)x)[(size_t)r * 32 + (i & 31)];
        ((float4*)sx)[i] = v;
    }
    __syncthreads();

    const int colq = threadIdx.x & 31;
    const int rowq = threadIdx.x >> 5;

    float acc[4][4];
#pragma unroll
    for (int r = 0; r < 4; ++r)
#pragma unroll
        for (int j = 0; j < 4; ++j) acc[r][j] = 0.f;

    for (int k = 0; k < 128; k += 4) {
        float4 wk0 = *(const float4*)&sW[(k + 0) * 128 + colq * 4];
        float4 wk1 = *(const float4*)&sW[(k + 1) * 128 + colq * 4];
        float4 wk2 = *(const float4*)&sW[(k + 2) * 128 + colq * 4];
        float4 wk3 = *(const float4*)&sW[(k + 3) * 128 + colq * 4];
#pragma unroll
        for (int r = 0; r < 4; ++r) {
            float4 xv = *(const float4*)&sx[(rowq * 4 + r) * 128 + k];
            acc[r][0] += xv.x * wk0.x + xv.y * wk1.x + xv.z * wk2.x + xv.w * wk3.x;
            acc[r][1] += xv.x * wk0.y + xv.y * wk1.y + xv.z * wk2.y + xv.w * wk3.y;
            acc[r][2] += xv.x * wk0.z + xv.y * wk1.z + xv.z * wk2.z + xv.w * wk3.z;
            acc[r][3] += xv.x * wk0.w + xv.y * wk1.w + xv.z * wk2.w + xv.w * wk3.w;
        }
    }

#pragma unroll
    for (int r = 0; r < 4; ++r) {
        int row = row0 + rowq * 4 + r;
        if (row < N_NODES) {
            ushort4 o;
            o.x = f2bf(acc[r][0]);
            o.y = f2bf(acc[r][1]);
            o.z = f2bf(acc[r][2]);
            o.w = f2bf(acc[r][3]);
            *(ushort4*)&y[(size_t)row * D + colq * 4] = o;
        }
    }
}

// ---------------------------------------------------------------------------
// K2 (1 block): per-bucket exclusive prefix over the 256 chunk-partials
// (in place) + Hillis-Steele scan of bucket totals -> bin_base[257].
// ---------------------------------------------------------------------------
__global__ __launch_bounds__(256) void scan_seeds(int* __restrict__ cnt_part,
                                                  int* __restrict__ bin_base) {
    __shared__ int s[256];
    const int t = threadIdx.x;
    int run = 0;
#pragma unroll 8
    for (int b = 0; b < NCHUNK; ++b) {
        int idx = b * BSTRIDE + t;
        int v = cnt_part[idx];
        cnt_part[idx] = run;     // per-(chunk,bucket) exclusive prefix
        run += v;
    }
    s[t] = run;                  // bucket total
    __syncthreads();
    for (int off = 1; off < 256; off <<= 1) {
        int v = (t >= off) ? s[t - off] : 0;
        __syncthreads();
        s[t] += v;
        __syncthreads();
    }
    bin_base[t] = (t == 0) ? 0 : s[t - 1];
    if (t == 255) bin_base[256] = s[255];
}

// ---------------------------------------------------------------------------
// K3: scatter edges into bucket segments via LDS cursors (no global atomics).
// Packed uint2: .x = (src<<16)|bf16(w), .y = dstlocal (0..39).
// ---------------------------------------------------------------------------
__global__ __launch_bounds__(256) void scatter_buckets(const int* __restrict__ src,
                                                       const int* __restrict__ dst,
                                                       const float* __restrict__ w,
                                                       const int* __restrict__ cnt_part,
                                                       const int* __restrict__ bin_base,
                                                       uint2* __restrict__ be) {
    __shared__ int cur[BSTRIDE];
    const int b = blockIdx.x;
    cur[threadIdx.x] = bin_base[threadIdx.x] + cnt_part[b * BSTRIDE + threadIdx.x];
    __syncthreads();
    const int e0 = b * CHUNK;
    for (int i = threadIdx.x; i < CHUNK; i += 256) {
        int e = e0 + i;
        int d = dst[e];
        int t = d / 40;
        int dl = d - t * 40;
        int pos = atomicAdd(&cur[t], 1);            // LDS atomic
        be[pos] = make_uint2(((unsigned int)src[e] << 16) | (unsigned int)f2bf(w[e]),
                             (unsigned int)dl);
    }
}

// ---------------------------------------------------------------------------
// K4: per bucket (40 nodes): load edges to registers, LDS counting-sort by
// dstlocal, then wave k gather-reduces nodes [k*10, k*10+10) with register
// accumulators and writes out rows directly (+bias). No global per-node CSR.
// ---------------------------------------------------------------------------
__global__ __launch_bounds__(256) void bucket_gather(const uint2* __restrict__ be,
                                                     const int* __restrict__ bin_base,
                                                     const unsigned short* __restrict__ y,
                                                     const float* __restrict__ bias,
                                                     float* __restrict__ out) {
    __shared__ uint2 sorted[CAP];    // 32 KB
    __shared__ int hcnt[40];
    __shared__ int binoff[41];
    __shared__ int cur[40];

    const int b   = blockIdx.x;
    const int tid = threadIdx.x;
    const int beg = bin_base[b];
    int cnt = bin_base[b + 1] - beg;
    if (cnt > CAP) cnt = CAP;        // unreachable for this dataset; OOB guard

    if (tid < 40) hcnt[tid] = 0;
    __syncthreads();

    // load my edges into registers + LDS histogram of dstlocal
    uint2 er[16];
#pragma unroll
    for (int k = 0; k < 16; ++k) {
        int i = k * 256 + tid;
        er[k].y = 0xFFFFFFFFu;
        if (i < cnt) {
            er[k] = be[beg + i];
            atomicAdd(&hcnt[er[k].y], 1);
        }
    }
    __syncthreads();

    if (tid == 0) {
        int run = 0;
#pragma unroll
        for (int i = 0; i < 40; ++i) {
            binoff[i] = run;
            cur[i]    = run;
            run += hcnt[i];
        }
        binoff[40] = run;
    }
    __syncthreads();

    // place into sorted order
#pragma unroll
    for (int k = 0; k < 16; ++k) {
        if (er[k].y != 0xFFFFFFFFu) {
            int pos = atomicAdd(&cur[er[k].y], 1);
            sorted[pos] = er[k];
        }
    }
    __syncthreads();

    // gather: wave wv owns nodes wv*10 .. wv*10+9
    const int wv   = tid >> 6;
    const int lane = tid & 63;
    const int g    = lane >> 4;   // slot group 0..3
    const int c    = lane & 15;   // owns cols c*8 .. c*8+7
    const float4 bb0 = *(const float4*)&bias[c * 8];
    const float4 bb1 = *(const float4*)&bias[c * 8 + 4];

    for (int q = 0; q < 10; ++q) {
        const int nl = wv * 10 + q;
        const int s0 = binoff[nl];
        const int s1 = binoff[nl + 1];

        float acc[8];
#pragma unroll
        for (int j = 0; j < 8; ++j) acc[j] = 0.f;

        int s = s0 + g;
        for (; s + 4 < s1; s += 8) {   // 2-deep for MLP
            uint2 e0 = sorted[s];
            uint2 e1 = sorted[s + 4];
            float w0 = __uint_as_float(e0.x << 16);
            float w1 = __uint_as_float(e1.x << 16);
            uint4 u0 = *(const uint4*)(y + (size_t)(e0.x >> 16) * D + c * 8);
            uint4 u1 = *(const uint4*)(y + (size_t)(e1.x >> 16) * D + c * 8);
            const unsigned int* p0 = (const unsigned int*)&u0;
            const unsigned int* p1 = (const unsigned int*)&u1;
#pragma unroll
            for (int t2 = 0; t2 < 4; ++t2) {
                acc[2 * t2]     += w0 * __uint_as_float(p0[t2] << 16);
                acc[2 * t2 + 1] += w0 * __uint_as_float(p0[t2] & 0xffff0000u);
            }
#pragma unroll
            for (int t2 = 0; t2 < 4; ++t2) {
                acc[2 * t2]     += w1 * __uint_as_float(p1[t2] << 16);
                acc[2 * t2 + 1] += w1 * __uint_as_float(p1[t2] & 0xffff0000u);
            }
        }
        for (; s < s1; s += 4) {
            uint2 e0 = sorted[s];
            float w0 = __uint_as_float(e0.x << 16);
            uint4 u0 = *(const uint4*)(y + (size_t)(e0.x >> 16) * D + c * 8);
            const unsigned int* p0 = (const unsigned int*)&u0;
#pragma unroll
            for (int t2 = 0; t2 < 4; ++t2) {
                acc[2 * t2]     += w0 * __uint_as_float(p0[t2] << 16);
                acc[2 * t2 + 1] += w0 * __uint_as_float(p0[t2] & 0xffff0000u);
            }
        }

#pragma unroll
        for (int j = 0; j < 8; ++j) {
            acc[j] += __shfl_xor(acc[j], 16, 64);
            acc[j] += __shfl_xor(acc[j], 32, 64);
        }

        if (g == 0) {
            const int node = b * 40 + nl;
            float4 r0 = make_float4(acc[0] + bb0.x, acc[1] + bb0.y,
                                    acc[2] + bb0.z, acc[3] + bb0.w);
            float4 r1 = make_float4(acc[4] + bb1.x, acc[5] + bb1.y,
                                    acc[6] + bb1.z, acc[7] + bb1.w);
            *(float4*)&out[(size_t)node * D + c * 8]     = r0;
            *(float4*)&out[(size_t)node * D + c * 8 + 4] = r1;
        }
    }
}

extern "C" void kernel_launch(void* const* d_in, const int* in_sizes, int n_in,
                              void* d_out, int out_size, void* d_ws, size_t ws_size,
                              hipStream_t stream) {
    const float* x    = (const float*)d_in[0];
    const int*   src  = (const int*)d_in[1];
    const int*   dst  = (const int*)d_in[2];
    const float* w    = (const float*)d_in[3];
    const float* W    = (const float*)d_in[4];
    const float* bias = (const float*)d_in[5];
    float* out = (float*)d_out;

    // workspace layout, total ~7.95 MB
    char* ws = (char*)d_ws;
    unsigned short* y        = (unsigned short*)(ws);        // 2,560,000 B (bf16)
    int*            cnt_part = (int*)(ws + 2560000);         // 256*256*4 = 262,144 B
    int*            bin_base = (int*)(ws + 2822144);         //     4,096 B (257 used)
    uint2*          be       = (uint2*)(ws + 2826240);       // 5,120,000 B

    // 1) bucket histograms || y = bf16(x @ W)
    hist_gemm<<<NCHUNK + GEMM_BLOCKS, 256, 0, stream>>>(x, W, dst, y, cnt_part);

    // 2) prefix over chunk partials + bucket bases (1 block)
    scan_seeds<<<1, 256, 0, stream>>>(cnt_part, bin_base);

    // 3) scatter edges into bucket segments
    scatter_buckets<<<NCHUNK, 256, 0, stream>>>(src, dst, w, cnt_part, bin_base, be);

    // 4) per-bucket counting sort + gather-reduce -> out (+bias)
    bucket_gather<<<NB, 256, 0, stream>>>(be, bin_base, y, bias, out);
}

// Round 7
// 69.447 us; speedup vs baseline: 1.1338x; 1.1338x over previous
//
#include <hip/hip_runtime.h>
#include <hip/hip_bf16.h>

#define N_NODES 10000
#define N_EDGES 640000
#define D 128

#define GEMM_BLOCKS 313        // ceil(10000/32)
#define BH 160                 // hist/fill blocks
#define CHUNK (N_EDGES / BH)   // 4000 edges per block
#define PSTRIDE 10016          // padded stride for cnt_part rows (u16)
#define BG 4                   // b-groups in reduce_prefix
#define BPG (BH / BG)          // 40 partials per group

__device__ __forceinline__ unsigned short f2bf(float f) {
    unsigned int u = __float_as_uint(f);
    unsigned int r = (u + 0x7fffu + ((u >> 16) & 1u)) >> 16;  // RNE
    return (unsigned short)r;
}

// ---------------------------------------------------------------------------
// K1: per-block LDS histogram of dst -> u16 partial counts (no global
// atomics). 160 blocks x 4000 edges, uint4 vector loads.
// ---------------------------------------------------------------------------
__global__ __launch_bounds__(256) void hist(const int* __restrict__ dst,
                                            unsigned short* __restrict__ cnt_part) {
    __shared__ int h[N_NODES];   // 40 KB
    for (int i = threadIdx.x; i < N_NODES; i += 256) h[i] = 0;
    __syncthreads();
    const uint4* d4 = (const uint4*)(dst + blockIdx.x * CHUNK);
    for (int i = threadIdx.x; i < CHUNK / 4; i += 256) {
        uint4 v = d4[i];
        atomicAdd(&h[v.x], 1);
        atomicAdd(&h[v.y], 1);
        atomicAdd(&h[v.z], 1);
        atomicAdd(&h[v.w], 1);
    }
    __syncthreads();
    unsigned short* row = cnt_part + (size_t)blockIdx.x * PSTRIDE;
    for (int i = threadIdx.x; i < N_NODES; i += 256)
        row[i] = (unsigned short)h[i];              // coalesced, non-atomic
}

// ---------------------------------------------------------------------------
// K2: per node n: exclusive prefix over the 160 block-partials (in place,
// u16) and total cnt[n]. Parallelized over the b-axis: 4 groups of 40
// partials each; group sums combined through LDS. 157 blocks x 256 threads.
// ---------------------------------------------------------------------------
__global__ __launch_bounds__(256) void reduce_prefix(unsigned short* __restrict__ cnt_part,
                                                     int* __restrict__ cnt) {
    __shared__ int s[64][BG + 1];   // +1 pad
    const int t  = threadIdx.x;
    const int nl = t & 63;
    const int g  = t >> 6;          // 0..3
    const int n  = blockIdx.x * 64 + nl;

    int sum = 0;
    if (n < N_NODES) {
        size_t base = (size_t)g * BPG * PSTRIDE + n;
#pragma unroll
        for (int b = 0; b < BPG; ++b)
            sum += cnt_part[base + (size_t)b * PSTRIDE];
    }
    s[nl][g] = sum;
    __syncthreads();

    if (n < N_NODES) {
        int run = 0;
        for (int gg = 0; gg < g; ++gg) run += s[nl][gg];
        size_t base = (size_t)g * BPG * PSTRIDE + n;
#pragma unroll
        for (int b = 0; b < BPG; ++b) {
            size_t idx = base + (size_t)b * PSTRIDE;
            int c = cnt_part[idx];
            cnt_part[idx] = (unsigned short)run;    // prefix <= degree << 65536
            run += c;
        }
        if (g == BG - 1) cnt[n] = run;              // total for node n
    }
}

// ---------------------------------------------------------------------------
// K3 (fused): blocks [0,BH): in-block scan of cnt -> seeds, then fill packed
// CSR values via LDS cursors (no global atomics). Block 0 also writes offs[].
// Blocks [BH, BH+GEMM_BLOCKS): y = bf16(x @ W). GEMM hides under the fill.
// ---------------------------------------------------------------------------
__global__ __launch_bounds__(256) void fill_gemm(const float* __restrict__ x,
                                                 const float* __restrict__ W,
                                                 const int* __restrict__ src,
                                                 const int* __restrict__ dst,
                                                 const float* __restrict__ w,
                                                 const int* __restrict__ cnt,
                                                 const unsigned short* __restrict__ cnt_part,
                                                 unsigned int* __restrict__ swv,
                                                 unsigned short* __restrict__ y,
                                                 int* __restrict__ offs) {
    __shared__ float sW[128 * 128];   // 64 KB: GEMM weights | fill cursors
    __shared__ float sx[32 * 128];    // 16 KB: GEMM x-tile  | fill scan temp

    if (blockIdx.x < BH) {
        // ---- fill block ----
        int* cur  = (int*)sW;         // 40 KB cursor table
        int* incl = (int*)sx;         // 256-entry scan array
        const int t = threadIdx.x;

        // redundant in-block exclusive scan of cnt[0..9999]
        int mysum = 0;
#pragma unroll 8
        for (int i = 0; i < 40; ++i) {
            int idx = t * 40 + i;
            if (idx < N_NODES) mysum += cnt[idx];
        }
        incl[t] = mysum;
        __syncthreads();
        for (int off = 1; off < 256; off <<= 1) {
            int v = (t >= off) ? incl[t - off] : 0;
            __syncthreads();
            incl[t] += v;
            __syncthreads();
        }
        int run = incl[t] - mysum;    // exclusive base of this thread's range

        const unsigned short* part = cnt_part + (size_t)blockIdx.x * PSTRIDE;
        const bool wb = (blockIdx.x == 0);
#pragma unroll 8
        for (int i = 0; i < 40; ++i) {
            int idx = t * 40 + i;
            if (idx < N_NODES) {
                cur[idx] = run + (int)part[idx];
                if (wb) offs[idx] = run;
                run += cnt[idx];
            }
        }
        if (wb && t == 255) offs[N_NODES] = incl[255];
        __syncthreads();

        // scatter this chunk's edges into their CSR slots
        const int e0 = blockIdx.x * CHUNK;
        for (int i = t; i < CHUNK; i += 256) {
            int e = e0 + i;
            int pos = atomicAdd(&cur[dst[e]], 1);   // LDS atomic
            swv[pos] = ((unsigned int)src[e] << 16) | (unsigned int)f2bf(w[e]);
        }
        return;
    }

    // ---- GEMM block ----
    const int row0 = (blockIdx.x - BH) * 32;

    for (int i = threadIdx.x; i < 128 * 128 / 4; i += 256)
        ((float4*)sW)[i] = ((const float4*)W)[i];
    for (int i = threadIdx.x; i < 32 * 128 / 4; i += 256) {
        int r = row0 + (i >> 5);
        float4 v = make_float4(0.f, 0.f, 0.f, 0.f);
        if (r < N_NODES) v = ((const float4*)x)[(size_t)r * 32 + (i & 31)];
        ((float4*)sx)[i] = v;
    }
    __syncthreads();

    const int colq = threadIdx.x & 31;
    const int rowq = threadIdx.x >> 5;

    float acc[4][4];
#pragma unroll
    for (int r = 0; r < 4; ++r)
#pragma unroll
        for (int j = 0; j < 4; ++j) acc[r][j] = 0.f;

    for (int k = 0; k < 128; k += 4) {
        float4 wk0 = *(const float4*)&sW[(k + 0) * 128 + colq * 4];
        float4 wk1 = *(const float4*)&sW[(k + 1) * 128 + colq * 4];
        float4 wk2 = *(const float4*)&sW[(k + 2) * 128 + colq * 4];
        float4 wk3 = *(const float4*)&sW[(k + 3) * 128 + colq * 4];
#pragma unroll
        for (int r = 0; r < 4; ++r) {
            float4 xv = *(const float4*)&sx[(rowq * 4 + r) * 128 + k];
            acc[r][0] += xv.x * wk0.x + xv.y * wk1.x + xv.z * wk2.x + xv.w * wk3.x;
            acc[r][1] += xv.x * wk0.y + xv.y * wk1.y + xv.z * wk2.y + xv.w * wk3.y;
            acc[r][2] += xv.x * wk0.z + xv.y * wk1.z + xv.z * wk2.z + xv.w * wk3.z;
            acc[r][3] += xv.x * wk0.w + xv.y * wk1.w + xv.z * wk2.w + xv.w * wk3.w;
        }
    }

#pragma unroll
    for (int r = 0; r < 4; ++r) {
        int row = row0 + rowq * 4 + r;
        if (row < N_NODES) {
            ushort4 o;
            o.x = f2bf(acc[r][0]);
            o.y = f2bf(acc[r][1]);
            o.z = f2bf(acc[r][2]);
            o.w = f2bf(acc[r][3]);
            *(ushort4*)&y[(size_t)row * D + colq * 4] = o;
        }
    }
}

// ---------------------------------------------------------------------------
// K4: one wave per node: out[n] = sum w*y_bf16[src] + bias.
// 4 groups of 16 lanes; packed u32 per slot; lane owns 8 bf16 cols (16B
// load). 4-deep unroll: 4 independent slot+row loads in flight per group.
// ---------------------------------------------------------------------------
__global__ __launch_bounds__(256) void gather_nodes(const unsigned short* __restrict__ y,
                                                    const int* __restrict__ offs,
                                                    const unsigned int* __restrict__ swv,
                                                    const float* __restrict__ bias,
                                                    float* __restrict__ out) {
    const int n = blockIdx.x * 4 + (threadIdx.x >> 6);
    if (n >= N_NODES) return;
    const int lane = threadIdx.x & 63;
    const int c    = lane & 15;   // cols c*8 .. c*8+7
    const int g    = lane >> 4;   // group 0..3

    const int beg = offs[n];
    const int end = offs[n + 1];

    float acc[8];
#pragma unroll
    for (int j = 0; j < 8; ++j) acc[j] = 0.f;

    int i = beg + g;
    for (; i + 12 < end; i += 16) {   // 4-deep
        unsigned int a0 = swv[i];
        unsigned int a1 = swv[i + 4];
        unsigned int a2 = swv[i + 8];
        unsigned int a3 = swv[i + 12];
        uint4 u0 = *(const uint4*)(y + (size_t)(a0 >> 16) * D + c * 8);
        uint4 u1 = *(const uint4*)(y + (size_t)(a1 >> 16) * D + c * 8);
        uint4 u2 = *(const uint4*)(y + (size_t)(a2 >> 16) * D + c * 8);
        uint4 u3 = *(const uint4*)(y + (size_t)(a3 >> 16) * D + c * 8);
        float w0 = __uint_as_float(a0 << 16);
        float w1 = __uint_as_float(a1 << 16);
        float w2 = __uint_as_float(a2 << 16);
        float w3 = __uint_as_float(a3 << 16);
        const unsigned int* p0 = (const unsigned int*)&u0;
        const unsigned int* p1 = (const unsigned int*)&u1;
        const unsigned int* p2 = (const unsigned int*)&u2;
        const unsigned int* p3 = (const unsigned int*)&u3;
#pragma unroll
        for (int q = 0; q < 4; ++q) {
            acc[2 * q]     += w0 * __uint_as_float(p0[q] << 16);
            acc[2 * q + 1] += w0 * __uint_as_float(p0[q] & 0xffff0000u);
            acc[2 * q]     += w1 * __uint_as_float(p1[q] << 16);
            acc[2 * q + 1] += w1 * __uint_as_float(p1[q] & 0xffff0000u);
            acc[2 * q]     += w2 * __uint_as_float(p2[q] << 16);
            acc[2 * q + 1] += w2 * __uint_as_float(p2[q] & 0xffff0000u);
            acc[2 * q]     += w3 * __uint_as_float(p3[q] << 16);
            acc[2 * q + 1] += w3 * __uint_as_float(p3[q] & 0xffff0000u);
        }
    }
    for (; i < end; i += 4) {
        unsigned int a0 = swv[i];
        float w0 = __uint_as_float(a0 << 16);
        uint4 u0 = *(const uint4*)(y + (size_t)(a0 >> 16) * D + c * 8);
        const unsigned int* p0 = (const unsigned int*)&u0;
#pragma unroll
        for (int q = 0; q < 4; ++q) {
            acc[2 * q]     += w0 * __uint_as_float(p0[q] << 16);
            acc[2 * q + 1] += w0 * __uint_as_float(p0[q] & 0xffff0000u);
        }
    }

#pragma unroll
    for (int j = 0; j < 8; ++j) {
        acc[j] += __shfl_xor(acc[j], 16, 64);
        acc[j] += __shfl_xor(acc[j], 32, 64);
    }

    if (g == 0) {
        float4 b0 = *(const float4*)&bias[c * 8];
        float4 b1 = *(const float4*)&bias[c * 8 + 4];
        float4 r0 = make_float4(acc[0] + b0.x, acc[1] + b0.y, acc[2] + b0.z, acc[3] + b0.w);
        float4 r1 = make_float4(acc[4] + b1.x, acc[5] + b1.y, acc[6] + b1.z, acc[7] + b1.w);
        *(float4*)&out[(size_t)n * D + c * 8]     = r0;
        *(float4*)&out[(size_t)n * D + c * 8 + 4] = r1;
    }
}

extern "C" void kernel_launch(void* const* d_in, const int* in_sizes, int n_in,
                              void* d_out, int out_size, void* d_ws, size_t ws_size,
                              hipStream_t stream) {
    const float* x    = (const float*)d_in[0];
    const int*   src  = (const int*)d_in[1];
    const int*   dst  = (const int*)d_in[2];
    const float* w    = (const float*)d_in[3];
    const float* W    = (const float*)d_in[4];
    const float* bias = (const float*)d_in[5];
    float* out = (float*)d_out;

    // workspace layout, total ~8.4 MB
    char* ws = (char*)d_ws;
    unsigned short* y        = (unsigned short*)(ws);          // 2,560,000 B (bf16)
    unsigned short* cnt_part = (unsigned short*)(ws + 2560000);// 160*10016*2 = 3,205,120 B
    int*            cnt      = (int*)(ws + 5765120);           //    40,960 B
    int*            offs     = (int*)(ws + 5806080);           //    40,960 B
    unsigned int*   swv      = (unsigned int*)(ws + 5847040);  // 2,560,000 B

    // 1) per-block LDS histograms (no global atomics)
    hist<<<BH, 256, 0, stream>>>(dst, cnt_part);

    // 2) per-node prefix over block partials (4-way parallel over b) + totals
    reduce_prefix<<<(N_NODES + 63) / 64, 256, 0, stream>>>(cnt_part, cnt);

    // 3) in-block scan + fill packed CSR (LDS cursors)  ||  y = bf16(x @ W)
    fill_gemm<<<BH + GEMM_BLOCKS, 256, 0, stream>>>(x, W, src, dst, w, cnt,
                                                    cnt_part, swv, y, offs);

    // 4) gather-reduce per node (+bias), 4-deep unrolled
    gather_nodes<<<(N_NODES + 3) / 4, 256, 0, stream>>>(y, offs, swv, bias, out);
}

// Round 8
// 52.820 us; speedup vs baseline: 1.4907x; 1.3148x over previous
//
#include <hip/hip_runtime.h>
#include <hip/hip_bf16.h>

#define N_NODES 10000
#define N_EDGES 640000
#define D 128

#define GEMM_BLOCKS 313        // ceil(10000/32)
#define BH 160                 // hist/fill blocks
#define CHUNK (N_EDGES / BH)   // 4000 edges per block
#define PSTRIDE 10016          // padded stride for cnt_part rows (u16)
#define BG 4                   // b-groups in reduce_prefix
#define BPG (BH / BG)          // 40 partials per group

__device__ __forceinline__ unsigned short f2bf(float f) {
    unsigned int u = __float_as_uint(f);
    unsigned int r = (u + 0x7fffu + ((u >> 16) & 1u)) >> 16;  // RNE
    return (unsigned short)r;
}

// ---------------------------------------------------------------------------
// K1: per-block LDS histogram of dst -> u16 partial counts (no global
// atomics). 160 blocks x 4000 edges, uint4 vector loads.
// ---------------------------------------------------------------------------
__global__ __launch_bounds__(256) void hist(const int* __restrict__ dst,
                                            unsigned short* __restrict__ cnt_part) {
    __shared__ int h[N_NODES];   // 40 KB
    for (int i = threadIdx.x; i < N_NODES; i += 256) h[i] = 0;
    __syncthreads();
    const uint4* d4 = (const uint4*)(dst + blockIdx.x * CHUNK);
    for (int i = threadIdx.x; i < CHUNK / 4; i += 256) {
        uint4 v = d4[i];
        atomicAdd(&h[v.x], 1);
        atomicAdd(&h[v.y], 1);
        atomicAdd(&h[v.z], 1);
        atomicAdd(&h[v.w], 1);
    }
    __syncthreads();
    unsigned short* row = cnt_part + (size_t)blockIdx.x * PSTRIDE;
    for (int i = threadIdx.x; i < N_NODES; i += 256)
        row[i] = (unsigned short)h[i];              // coalesced, non-atomic
}

// ---------------------------------------------------------------------------
// K2: per node n: exclusive prefix over the 160 block-partials (in place,
// u16) and total cnt[n]. 4-way parallel over the b-axis; group sums combined
// through LDS. 157 blocks x 256 threads. (R7 version — kept, it worked.)
// ---------------------------------------------------------------------------
__global__ __launch_bounds__(256) void reduce_prefix(unsigned short* __restrict__ cnt_part,
                                                     int* __restrict__ cnt) {
    __shared__ int s[64][BG + 1];   // +1 pad
    const int t  = threadIdx.x;
    const int nl = t & 63;
    const int g  = t >> 6;          // 0..3
    const int n  = blockIdx.x * 64 + nl;

    int sum = 0;
    if (n < N_NODES) {
        size_t base = (size_t)g * BPG * PSTRIDE + n;
#pragma unroll
        for (int b = 0; b < BPG; ++b)
            sum += cnt_part[base + (size_t)b * PSTRIDE];
    }
    s[nl][g] = sum;
    __syncthreads();

    if (n < N_NODES) {
        int run = 0;
        for (int gg = 0; gg < g; ++gg) run += s[nl][gg];
        size_t base = (size_t)g * BPG * PSTRIDE + n;
#pragma unroll
        for (int b = 0; b < BPG; ++b) {
            size_t idx = base + (size_t)b * PSTRIDE;
            int c = cnt_part[idx];
            cnt_part[idx] = (unsigned short)run;
            run += c;
        }
        if (g == BG - 1) cnt[n] = run;              // total for node n
    }
}

// ---------------------------------------------------------------------------
// K3: 1-block exclusive scan of cnt -> offs[10001]. Wave-shuffle scan:
// per-thread serial 10, shfl_up within wave, 16 wave sums scanned by wave 0.
// Only 2 barriers (vs 20 in Hillis-Steele version).
// ---------------------------------------------------------------------------
__global__ __launch_bounds__(1024) void scan_offsets(const int* __restrict__ cnt,
                                                     int* __restrict__ offs) {
    __shared__ int wsum[16];
    const int t    = threadIdx.x;
    const int lane = t & 63;
    const int wid  = t >> 6;
    const int base = t * 10;

    int local[10];
    int s = 0;
#pragma unroll
    for (int i = 0; i < 10; ++i) {
        int v = (base + i < N_NODES) ? cnt[base + i] : 0;
        local[i] = s;
        s += v;
    }

    // inclusive scan of s across the wave
    int incl = s;
#pragma unroll
    for (int d = 1; d < 64; d <<= 1) {
        int v = __shfl_up(incl, d, 64);
        if (lane >= d) incl += v;
    }
    if (lane == 63) wsum[wid] = incl;
    __syncthreads();

    if (wid == 0 && lane < 16) {
        int v = wsum[lane];
        int wi = v;
#pragma unroll
        for (int d = 1; d < 16; d <<= 1) {
            int u = __shfl_up(wi, d, 64);
            if (lane >= d) wi += u;
        }
        wsum[lane] = wi - v;      // exclusive wave base
    }
    __syncthreads();

    int pre = wsum[wid] + incl - s;   // exclusive base for this thread
#pragma unroll
    for (int i = 0; i < 10; ++i)
        if (base + i < N_NODES) offs[base + i] = pre + local[i];
    if (t == 1023) offs[N_NODES] = wsum[15] + incl;   // wid==15: total
}

// ---------------------------------------------------------------------------
// K4 (fused): blocks [0,BH) fill the CSR value array via LDS cursors
// (one packed u32 = (src<<16)|bf16(w) per edge); blocks [BH,BH+GEMM_BLOCKS)
// compute y = bf16(x @ W). (Exact R5 version — the R7 in-block scan is gone.)
// ---------------------------------------------------------------------------
__global__ __launch_bounds__(256) void fill_gemm(const float* __restrict__ x,
                                                 const float* __restrict__ W,
                                                 const int* __restrict__ src,
                                                 const int* __restrict__ dst,
                                                 const float* __restrict__ w,
                                                 const int* __restrict__ offs,
                                                 const unsigned short* __restrict__ cnt_part,
                                                 unsigned int* __restrict__ swv,
                                                 unsigned short* __restrict__ y) {
    __shared__ float sW[128 * 128];   // 64 KB (fill blocks reuse as cursors)
    __shared__ float sx[32 * 128];    // 16 KB

    if (blockIdx.x < BH) {
        // ---- fill block ----
        int* cur = (int*)sW;          // 40 KB cursor table
        const int b = blockIdx.x;
        const unsigned short* part = cnt_part + (size_t)b * PSTRIDE;
        for (int i = threadIdx.x; i < N_NODES; i += 256)
            cur[i] = offs[i] + (int)part[i];        // coalesced, bank-clean
        __syncthreads();
        const int e0 = b * CHUNK;
        for (int i = threadIdx.x; i < CHUNK; i += 256) {
            int e = e0 + i;
            int pos = atomicAdd(&cur[dst[e]], 1);   // LDS atomic
            swv[pos] = ((unsigned int)src[e] << 16) | (unsigned int)f2bf(w[e]);
        }
        return;
    }

    // ---- GEMM block ----
    const int row0 = (blockIdx.x - BH) * 32;

    for (int i = threadIdx.x; i < 128 * 128 / 4; i += 256)
        ((float4*)sW)[i] = ((const float4*)W)[i];
    for (int i = threadIdx.x; i < 32 * 128 / 4; i += 256) {
        int r = row0 + (i >> 5);
        float4 v = make_float4(0.f, 0.f, 0.f, 0.f);
        if (r < N_NODES) v = ((const float4*)x)[(size_t)r * 32 + (i & 31)];
        ((float4*)sx)[i] = v;
    }
    __syncthreads();

    const int colq = threadIdx.x & 31;
    const int rowq = threadIdx.x >> 5;

    float acc[4][4];
#pragma unroll
    for (int r = 0; r < 4; ++r)
#pragma unroll
        for (int j = 0; j < 4; ++j) acc[r][j] = 0.f;

    for (int k = 0; k < 128; k += 4) {
        float4 wk0 = *(const float4*)&sW[(k + 0) * 128 + colq * 4];
        float4 wk1 = *(const float4*)&sW[(k + 1) * 128 + colq * 4];
        float4 wk2 = *(const float4*)&sW[(k + 2) * 128 + colq * 4];
        float4 wk3 = *(const float4*)&sW[(k + 3) * 128 + colq * 4];
#pragma unroll
        for (int r = 0; r < 4; ++r) {
            float4 xv = *(const float4*)&sx[(rowq * 4 + r) * 128 + k];
            acc[r][0] += xv.x * wk0.x + xv.y * wk1.x + xv.z * wk2.x + xv.w * wk3.x;
            acc[r][1] += xv.x * wk0.y + xv.y * wk1.y + xv.z * wk2.y + xv.w * wk3.y;
            acc[r][2] += xv.x * wk0.z + xv.y * wk1.z + xv.z * wk2.z + xv.w * wk3.z;
            acc[r][3] += xv.x * wk0.w + xv.y * wk1.w + xv.z * wk2.w + xv.w * wk3.w;
        }
    }

#pragma unroll
    for (int r = 0; r < 4; ++r) {
        int row = row0 + rowq * 4 + r;
        if (row < N_NODES) {
            ushort4 o;
            o.x = f2bf(acc[r][0]);
            o.y = f2bf(acc[r][1]);
            o.z = f2bf(acc[r][2]);
            o.w = f2bf(acc[r][3]);
            *(ushort4*)&y[(size_t)row * D + colq * 4] = o;
        }
    }
}

// ---------------------------------------------------------------------------
// K5: one wave per node: out[n] = sum w*y_bf16[src] + bias.
// 4 groups of 16 lanes; packed u32 per slot; lane owns 8 bf16 cols (16B
// load). 4-deep unroll (R7 version — kept).
// ---------------------------------------------------------------------------
__global__ __launch_bounds__(256) void gather_nodes(const unsigned short* __restrict__ y,
                                                    const int* __restrict__ offs,
                                                    const unsigned int* __restrict__ swv,
                                                    const float* __restrict__ bias,
                                                    float* __restrict__ out) {
    const int n = blockIdx.x * 4 + (threadIdx.x >> 6);
    if (n >= N_NODES) return;
    const int lane = threadIdx.x & 63;
    const int c    = lane & 15;   // cols c*8 .. c*8+7
    const int g    = lane >> 4;   // group 0..3

    const int beg = offs[n];
    const int end = offs[n + 1];

    float acc[8];
#pragma unroll
    for (int j = 0; j < 8; ++j) acc[j] = 0.f;

    int i = beg + g;
    for (; i + 12 < end; i += 16) {   // 4-deep
        unsigned int a0 = swv[i];
        unsigned int a1 = swv[i + 4];
        unsigned int a2 = swv[i + 8];
        unsigned int a3 = swv[i + 12];
        uint4 u0 = *(const uint4*)(y + (size_t)(a0 >> 16) * D + c * 8);
        uint4 u1 = *(const uint4*)(y + (size_t)(a1 >> 16) * D + c * 8);
        uint4 u2 = *(const uint4*)(y + (size_t)(a2 >> 16) * D + c * 8);
        uint4 u3 = *(const uint4*)(y + (size_t)(a3 >> 16) * D + c * 8);
        float w0 = __uint_as_float(a0 << 16);
        float w1 = __uint_as_float(a1 << 16);
        float w2 = __uint_as_float(a2 << 16);
        float w3 = __uint_as_float(a3 << 16);
        const unsigned int* p0 = (const unsigned int*)&u0;
        const unsigned int* p1 = (const unsigned int*)&u1;
        const unsigned int* p2 = (const unsigned int*)&u2;
        const unsigned int* p3 = (const unsigned int*)&u3;
#pragma unroll
        for (int q = 0; q < 4; ++q) {
            acc[2 * q]     += w0 * __uint_as_float(p0[q] << 16);
            acc[2 * q + 1] += w0 * __uint_as_float(p0[q] & 0xffff0000u);
            acc[2 * q]     += w1 * __uint_as_float(p1[q] << 16);
            acc[2 * q + 1] += w1 * __uint_as_float(p1[q] & 0xffff0000u);
            acc[2 * q]     += w2 * __uint_as_float(p2[q] << 16);
            acc[2 * q + 1] += w2 * __uint_as_float(p2[q] & 0xffff0000u);
            acc[2 * q]     += w3 * __uint_as_float(p3[q] << 16);
            acc[2 * q + 1] += w3 * __uint_as_float(p3[q] & 0xffff0000u);
        }
    }
    for (; i < end; i += 4) {
        unsigned int a0 = swv[i];
        float w0 = __uint_as_float(a0 << 16);
        uint4 u0 = *(const uint4*)(y + (size_t)(a0 >> 16) * D + c * 8);
        const unsigned int* p0 = (const unsigned int*)&u0;
#pragma unroll
        for (int q = 0; q < 4; ++q) {
            acc[2 * q]     += w0 * __uint_as_float(p0[q] << 16);
            acc[2 * q + 1] += w0 * __uint_as_float(p0[q] & 0xffff0000u);
        }
    }

#pragma unroll
    for (int j = 0; j < 8; ++j) {
        acc[j] += __shfl_xor(acc[j], 16, 64);
        acc[j] += __shfl_xor(acc[j], 32, 64);
    }

    if (g == 0) {
        float4 b0 = *(const float4*)&bias[c * 8];
        float4 b1 = *(const float4*)&bias[c * 8 + 4];
        float4 r0 = make_float4(acc[0] + b0.x, acc[1] + b0.y, acc[2] + b0.z, acc[3] + b0.w);
        float4 r1 = make_float4(acc[4] + b1.x, acc[5] + b1.y, acc[6] + b1.z, acc[7] + b1.w);
        *(float4*)&out[(size_t)n * D + c * 8]     = r0;
        *(float4*)&out[(size_t)n * D + c * 8 + 4] = r1;
    }
}

extern "C" void kernel_launch(void* const* d_in, const int* in_sizes, int n_in,
                              void* d_out, int out_size, void* d_ws, size_t ws_size,
                              hipStream_t stream) {
    const float* x    = (const float*)d_in[0];
    const int*   src  = (const int*)d_in[1];
    const int*   dst  = (const int*)d_in[2];
    const float* w    = (const float*)d_in[3];
    const float* W    = (const float*)d_in[4];
    const float* bias = (const float*)d_in[5];
    float* out = (float*)d_out;

    // workspace layout, total ~8.4 MB
    char* ws = (char*)d_ws;
    unsigned short* y        = (unsigned short*)(ws);          // 2,560,000 B (bf16)
    unsigned short* cnt_part = (unsigned short*)(ws + 2560000);// 160*10016*2 = 3,205,120 B
    int*            cnt      = (int*)(ws + 5765120);           //    40,960 B
    int*            offs     = (int*)(ws + 5806080);           //    40,960 B
    unsigned int*   swv      = (unsigned int*)(ws + 5847040);  // 2,560,000 B

    // 1) per-block LDS histograms (no global atomics)
    hist<<<BH, 256, 0, stream>>>(dst, cnt_part);

    // 2) per-node prefix over block partials (4-way parallel over b) + totals
    reduce_prefix<<<(N_NODES + 63) / 64, 256, 0, stream>>>(cnt_part, cnt);

    // 3) exclusive scan -> offs (wave-shuffle, 2 barriers)
    scan_offsets<<<1, 1024, 0, stream>>>(cnt, offs);

    // 4) fill packed CSR (LDS cursors)  ||  y = bf16(x @ W)
    fill_gemm<<<BH + GEMM_BLOCKS, 256, 0, stream>>>(x, W, src, dst, w, offs,
                                                    cnt_part, swv, y);

    // 5) gather-reduce per node (+bias), 4-deep unrolled
    gather_nodes<<<(N_NODES + 3) / 4, 256, 0, stream>>>(y, offs, swv, bias, out);
}